// Round 11
// baseline (182.245 us; speedup 1.0000x reference)
//
#include <hip/hip_runtime.h>
#include <math.h>
#include <stdint.h>

#define NCLS   80
#define NPTS   8400
#define KEEP   100
#define PRETOPK 5000
#define NB     8
#define THRBITS 0x3C23D70Au   // bits of 0.01f (scores positive floats -> int-ordered)
#define BASEK   0x3C000000u   // all candidate keys in (THRBITS, 0x3F800000): key-BASEK is 26-bit

#define TBS    512            // select block size (8 waves)
#define NBLK   512            // persistent blocks: exactly 2 per CU; items stolen dynamically
#define CAPF   320            // candidate cap
#define NEEDF  128u           // selection target (>= KEEP; phase-8 continuation is exact regardless)
#define MTX    256            // suppression-matrix size
#define NW4    2100           // NPTS / 4 (uint4 words)

#define TBT    1024           // topk block size
#define NREGT  8              // 8000/1024
#define CAPT   512

__device__ __forceinline__ float sigmoidf_(float x) { return 1.0f / (1.0f + expf(-x)); }

__device__ __forceinline__ float4 decode_one(int n, int b,
        const float* bb0, const float* bb1, const float* bb2) {
    const float* bb; int base, HW, x, y; float s;
    if (n < 6400)      { bb = bb0; base = n;        HW = 6400; s = 8.f;  y = base / 80; x = base - y * 80; }
    else if (n < 8000) { bb = bb1; base = n - 6400; HW = 1600; s = 16.f; y = base / 40; x = base - y * 40; }
    else               { bb = bb2; base = n - 8000; HW = 400;  s = 32.f; y = base / 20; x = base - y * 20; }
    const float* p = bb + (size_t)b * 4 * HW + base;
    float v0 = p[0], v1 = p[HW], v2 = p[2 * HW], v3 = p[3 * HW];
    float cx = v0 * s + x * s, cy = v1 * s + y * s;
    float w = expf(v2) * s, h = expf(v3) * s;
    return make_float4(cx - 0.5f * w, cy - 0.5f * h, cx + 0.5f * w, cy + 0.5f * h);
}

__device__ __forceinline__ bool iou_gt(float4 a, float4 c) {
    float tlx = fmaxf(a.x, c.x), tly = fmaxf(a.y, c.y);
    float brx = fminf(a.z, c.z), bry = fminf(a.w, c.w);
    float w = fmaxf(brx - tlx, 0.f), h = fmaxf(bry - tly, 0.f);
    float inter = w * h;
    float a1 = (a.z - a.x) * (a.w - a.y);
    float a2 = (c.z - c.x) * (c.w - c.y);
    return inter / (a1 + a2 - inter + 1e-6f) > 0.65f;
}

// position of the r-th (0-based) set bit of v; precondition r < popcll(v)
__device__ __forceinline__ int nth_set_bit(unsigned long long v, int r) {
    int pos = 0;
    uint32_t x = (uint32_t)v;
    int c = __popc(x);
    if (r >= c) { r -= c; x = (uint32_t)(v >> 32); pos = 32; }
    c = __popc(x & 0xFFFFu); if (r >= c) { r -= c; x >>= 16; pos += 16; }
    c = __popc(x & 0xFFu);   if (r >= c) { r -= c; x >>= 8;  pos += 8; }
    c = __popc(x & 0xFu);    if (r >= c) { r -= c; x >>= 4;  pos += 4; }
    c = __popc(x & 0x3u);    if (r >= c) { r -= c; x >>= 2;  pos += 2; }
    c = __popc(x & 0x1u);    if (r >= c) { pos += 1; }
    return pos;
}

// ---- shared radix-scan helpers (operate on rebased 26-bit keys) ----
__device__ __forceinline__ void scan_hist1024(const uint32_t* sHist, uint32_t need, uint32_t cap,
                                              uint32_t carry, uint32_t prefix, int shift,
                                              uint32_t* shr, int lane) {
    const uint4* hv = (const uint4*)sHist;
    uint4 q0 = hv[lane * 4], q1 = hv[lane * 4 + 1], q2 = hv[lane * 4 + 2], q3 = hv[lane * 4 + 3];
    uint32_t csum = q0.x + q0.y + q0.z + q0.w + q1.x + q1.y + q1.z + q1.w
                  + q2.x + q2.y + q2.z + q2.w + q3.x + q3.y + q3.z + q3.w;
    uint32_t suf = csum;
    #pragma unroll
    for (int d = 1; d < 64; d <<= 1) {
        uint32_t t = (uint32_t)__shfl_down((int)suf, d);
        if (lane + d < 64) suf += t;
    }
    unsigned long long m = __ballot(carry + suf >= need);
    if (!m) { if (lane == 0) { shr[1] = 0u; shr[0] = 0u; } return; }
    int l1 = 63 - __clzll(m);
    uint32_t carry2 = carry + (uint32_t)__shfl((int)suf, l1) - (uint32_t)__shfl((int)csum, l1);
    uint32_t c2 = (lane < 16) ? sHist[l1 * 16 + lane] : 0u;
    uint32_t suf2 = c2;
    #pragma unroll
    for (int d = 1; d < 16; d <<= 1) {
        uint32_t t = (uint32_t)__shfl_down((int)suf2, d);
        if (lane + d < 16) suf2 += t;
    }
    unsigned long long m2 = __ballot(lane < 16 && (carry2 + suf2 >= need));
    int t2 = m2 ? (63 - __clzll(m2)) : 0;
    uint32_t suf2L = (uint32_t)__shfl((int)suf2, t2);
    uint32_t c2L   = (uint32_t)__shfl((int)c2, t2);
    int bin = l1 * 16 + t2;
    uint32_t cAbove = carry2 + suf2L - c2L;
    uint32_t cntIncl = cAbove + c2L;
    if (lane == 0) {
        if (cntIncl <= cap) { shr[1] = 0u; shr[0] = prefix | ((uint32_t)bin << shift); }
        else { shr[1] = 1u; shr[2] = prefix | ((uint32_t)bin << shift); shr[3] = cAbove; }
    }
}

__device__ __forceinline__ void scan_hist64_final(const uint32_t* sHist, uint32_t need, uint32_t cap,
                                                  uint32_t carry, uint32_t prefix,
                                                  uint32_t* shr, int lane) {
    uint32_t c2 = sHist[lane];
    uint32_t suf2 = c2;
    #pragma unroll
    for (int d = 1; d < 64; d <<= 1) {
        uint32_t t = (uint32_t)__shfl_down((int)suf2, d);
        if (lane + d < 64) suf2 += t;
    }
    unsigned long long m2 = __ballot(carry + suf2 >= need);
    int t2 = m2 ? (63 - __clzll(m2)) : 0;
    uint32_t suf2L = (uint32_t)__shfl((int)suf2, t2);
    uint32_t c2L   = (uint32_t)__shfl((int)c2, t2);
    uint32_t cAbove = carry + suf2L - c2L;
    uint32_t cntIncl = cAbove + c2L;
    if (lane == 0) {
        shr[1] = 0u;
        shr[0] = (cntIncl <= cap) ? (prefix | (uint32_t)t2)
                                  : ((prefix | (uint32_t)t2) + 1u);  // exclude exact tie-key; continuation recovers
    }
}

// ================================================================ fused per-(b,c) select + sort + NMS
// PERSISTENT + work-stealing: NBLK=512 blocks (2/CU), 640 items pulled from gIdx.
// Fixes the 3-vs-2-blocks/CU makespan quantization (640 = 2*256 + 128).
// LDS: sKey 33600 + uMem 8192 + sKeyS 1280 + sIdxS 640 + bBoxS 5120 + shr 16 + sh64 8 = 48856.
// uMem aliases: { sHist(4096) + cPack(2688) } <-> colM(8192); barriers separate lifetimes.
__global__ __launch_bounds__(TBS, 6)
void select_nms(const float* __restrict__ cls0, const float* __restrict__ bb0,
                const float* __restrict__ o0,
                const float* __restrict__ cls1, const float* __restrict__ bb1,
                const float* __restrict__ o1,
                const float* __restrict__ cls2, const float* __restrict__ bb2,
                const float* __restrict__ o2,
                uint32_t* __restrict__ gIdx,
                float* __restrict__ keptScore, float4* __restrict__ keptBox) {
    __shared__ __align__(16) uint32_t sKey[NPTS];                // 33.6 KB
    __shared__ __align__(16) char uMem[8192];                    // 8 KB (aliased)
    __shared__ uint32_t sKeyS[CAPF];
    __shared__ uint16_t sIdxS[CAPF];
    __shared__ __align__(16) float4 bBoxS[CAPF];
    __shared__ uint32_t shr[4];
    __shared__ unsigned long long sh64;

    uint32_t* sHist = (uint32_t*)uMem;                           // 4096 B
    unsigned long long* cPack = (unsigned long long*)(uMem + 4096); // (CAPF+16)*8 = 2688 B
    typedef unsigned long long ull4[4];
    ull4* colM = (ull4*)uMem;                                    // 8192 B, aliases sHist+cPack

    int tid = threadIdx.x, lane = tid & 63;

    for (;;) {
        // ---- steal next (b,c) item; block-uniform broadcast via LDS
        __syncthreads();                 // protects shr reuse across iterations
        if (tid == 0) shr[0] = atomicAdd(gIdx, 1u);
        __syncthreads();
        int item = (int)shr[0];
        if (item >= NB * NCLS) return;   // uniform exit
        int b = item & 7;
        int c = item >> 3;

        // ---- phase 1: keygen (float4 loads, fused obj sigmoid) -> LDS + rebased level-0 histogram
        sHist[tid] = 0; sHist[tid + TBS] = 0;
        __syncthreads();
        uint4* sKey4 = (uint4*)sKey;
        #pragma unroll
        for (int i = 0; i < 5; ++i) {
            int w = tid + i * TBS;
            if (w < NW4) {
                int n = w << 2;
                const float* cp; const float* op;
                if (w < 1600)      { cp = cls0 + ((size_t)b * NCLS + c) * 6400 + n;          op = o0 + (size_t)b * 6400 + n; }
                else if (w < 2000) { cp = cls1 + ((size_t)b * NCLS + c) * 1600 + (n - 6400); op = o1 + (size_t)b * 1600 + (n - 6400); }
                else               { cp = cls2 + ((size_t)b * NCLS + c) * 400 + (n - 8000);  op = o2 + (size_t)b * 400 + (n - 8000); }
                float4 cv = *(const float4*)cp;
                float4 ov = *(const float4*)op;
                uint32_t k0 = __float_as_uint(sigmoidf_(cv.x) * sigmoidf_(ov.x));
                uint32_t k1 = __float_as_uint(sigmoidf_(cv.y) * sigmoidf_(ov.y));
                uint32_t k2 = __float_as_uint(sigmoidf_(cv.z) * sigmoidf_(ov.z));
                uint32_t k3 = __float_as_uint(sigmoidf_(cv.w) * sigmoidf_(ov.w));
                sKey4[w] = make_uint4(k0, k1, k2, k3);
                if (k0 > THRBITS) atomicAdd(&sHist[(k0 - BASEK) >> 16], 1u);
                if (k1 > THRBITS) atomicAdd(&sHist[(k1 - BASEK) >> 16], 1u);
                if (k2 > THRBITS) atomicAdd(&sHist[(k2 - BASEK) >> 16], 1u);
                if (k3 > THRBITS) atomicAdd(&sHist[(k3 - BASEK) >> 16], 1u);
            }
        }
        __syncthreads();

        // ---- phase 2: exact radix threshold selection on 26-bit rebased keys (10/10/6 bits)
        uint32_t prefix = 0, carry = 0, Tsel = 0;
        const uint4* k4 = (const uint4*)sKey;
        for (int level = 0;; ++level) {
            if (tid < 64) {
                if (level < 2) scan_hist1024(sHist, NEEDF, CAPF, carry, prefix, level == 0 ? 16 : 6, shr, lane);
                else           scan_hist64_final(sHist, NEEDF, CAPF, carry, prefix, shr, lane);
            }
            __syncthreads();
            if (shr[1] == 0u) { Tsel = shr[0]; break; }
            prefix = shr[2]; carry = shr[3];
            int nl = level + 1;
            if (nl == 2) { if (tid < 64) sHist[tid] = 0; } else { sHist[tid] = 0; sHist[tid + TBS] = 0; }
            __syncthreads();
            #pragma unroll
            for (int i = 0; i < 5; ++i) {
                int w = tid + i * TBS;
                if (w < NW4) {
                    uint4 q = k4[w];
                    #pragma unroll
                    for (int j = 0; j < 4; ++j) {
                        uint32_t k = (j == 0) ? q.x : (j == 1) ? q.y : (j == 2) ? q.z : q.w;
                        if (k > THRBITS) {
                            uint32_t kp = k - BASEK;
                            if (nl == 1) { if ((kp >> 16) == (prefix >> 16)) atomicAdd(&sHist[(kp >> 6) & 1023u], 1u); }
                            else         { if ((kp >> 6)  == (prefix >> 6))  atomicAdd(&sHist[kp & 63u], 1u); }
                        }
                    }
                }
            }
            __syncthreads();
        }
        __syncthreads();
        if (tid == 0) shr[3] = 0u;
        __syncthreads();

        // ---- phase 3: compact from LDS keys (packed u64: key<<32 | (0xFFFF - n))
        #pragma unroll
        for (int i = 0; i < 5; ++i) {
            int w = tid + i * TBS;
            if (w < NW4) {
                uint4 q = k4[w];
                int n = w << 2;
                #pragma unroll
                for (int j = 0; j < 4; ++j) {
                    uint32_t k = (j == 0) ? q.x : (j == 1) ? q.y : (j == 2) ? q.z : q.w;
                    if (k > THRBITS && (k - BASEK) >= Tsel) {
                        uint32_t s = atomicAdd(&shr[3], 1u);
                        if (s < CAPF) cPack[s] = ((unsigned long long)k << 32) | (uint32_t)(0xFFFFu - (n + j));
                    }
                }
            }
        }
        __syncthreads();
        int cnt = (int)shr[3]; if (cnt > CAPF) cnt = CAPF;
        if (tid < 16) cPack[cnt + tid] = 0ull;
        __syncthreads();

        // ---- phase 4: rank-sort, participating waves only, 16 cands/iter (b128 reads)
        if (tid < ((cnt + 63) & ~63)) {
            bool h0 = tid < cnt;
            unsigned long long my = h0 ? cPack[tid] : 0ull;
            int r0 = 0;
            const ulonglong2* cp2 = (const ulonglong2*)cPack;
            int nb16 = (cnt + 15) >> 4;
            for (int jb = 0; jb < nb16; ++jb) {
                ulonglong2 p0 = cp2[jb * 8 + 0], p1 = cp2[jb * 8 + 1], p2 = cp2[jb * 8 + 2], p3 = cp2[jb * 8 + 3];
                ulonglong2 p4 = cp2[jb * 8 + 4], p5 = cp2[jb * 8 + 5], p6 = cp2[jb * 8 + 6], p7 = cp2[jb * 8 + 7];
                r0 += (p0.x > my) + (p0.y > my) + (p1.x > my) + (p1.y > my)
                    + (p2.x > my) + (p2.y > my) + (p3.x > my) + (p3.y > my)
                    + (p4.x > my) + (p4.y > my) + (p5.x > my) + (p5.y > my)
                    + (p6.x > my) + (p6.y > my) + (p7.x > my) + (p7.y > my);
            }
            if (h0) {
                sKeyS[r0] = (uint32_t)(my >> 32);
                sIdxS[r0] = (uint16_t)(0xFFFFu - (uint32_t)(my & 0xFFFFu));
            }
        }
        __syncthreads();

        // ---- phase 5: gather + inline-decode candidate boxes
        if (tid < cnt) bBoxS[tid] = decode_one(sIdxS[tid], b, bb0, bb1, bb2);
        __syncthreads();
        // (cPack/sHist dead from here on; colM may now overwrite uMem)

        // ---- phase 6: UPPER-TRIANGLE suppression bitmatrix (exact: walk only consumes j>i bits)
        int lim = (cnt < MTX) ? cnt : MTX;
        #pragma unroll
        for (int pp = 0; pp < 2; ++pp) {
            int t2 = tid + pp * TBS;
            int cand = t2 & 255, rb = t2 >> 8;
            int j0 = rb << 6;
            unsigned long long m = 0ull;
            if (cand < lim && j0 + 63 > cand) {
                float4 bcx = bBoxS[cand];
                #pragma unroll 8
                for (int jj = 0; jj < 64; ++jj)
                    if (iou_gt(bBoxS[j0 + jj], bcx)) m |= 1ull << jj;
                if (j0 <= cand) m &= ~((2ull << (cand - j0)) - 1ull);  // keep only j > cand
            }
            colM[cand][rb] = m;
        }
        __syncthreads();

        // ---- phase 7: batch probes (all-kept fast path) + serial walk engine (exact greedy)
        float4 kb0 = make_float4(0.f, 0.f, 0.f, 0.f), kb1 = kb0;
        float ks0 = -1.0f, ks1 = -1.0f;
        int K = 0;
        if (tid < 64) {
            __builtin_amdgcn_s_setprio(1);
            unsigned long long U0, U1, U2, U3;
            U0 = (lim >= 64) ? ~0ull : ((lim > 0) ? ((1ull << lim) - 1) : 0ull);
            U1 = (lim >= 128) ? ~0ull : ((lim > 64) ? ((1ull << (lim - 64)) - 1) : 0ull);
            U2 = (lim >= 192) ? ~0ull : ((lim > 128) ? ((1ull << (lim - 128)) - 1) : 0ull);
            U3 = (lim >= 256) ? ~0ull : ((lim > 192) ? ((1ull << (lim - 192)) - 1) : 0ull);
            int kIA = -1, kIB = -1;

            // probe A: first n0=min(lim,64) candidates mutually non-suppressing? -> keep all at once
            int n0 = (lim < 64) ? lim : 64;
            if (n0 > 0) {
                ulonglong2 rlo = *(const ulonglong2*)&colM[lane][0];
                ulonglong2 rhi = *(const ulonglong2*)&colM[lane][2];
                bool mem = lane < n0;
                unsigned long long v0 = mem ? rlo.x : 0ull, v1 = mem ? rlo.y : 0ull;
                unsigned long long v2 = mem ? rhi.x : 0ull, v3 = mem ? rhi.y : 0ull;
                #pragma unroll
                for (int d = 1; d < 64; d <<= 1) {
                    v0 |= __shfl_xor(v0, d); v1 |= __shfl_xor(v1, d);
                    v2 |= __shfl_xor(v2, d); v3 |= __shfl_xor(v3, d);
                }
                if ((v0 & U0) == 0ull) {
                    if (lane < n0) kIA = lane;      // keep-index lane <- candidate lane
                    K = n0;
                    U0 = 0ull; U1 &= ~v1; U2 &= ~v2; U3 &= ~v3;
                    // probe B: next need=KEEP-K remaining candidates of chunk 1 (K==64 here iff lim>64)
                    if (lim > 64 && U1 != 0ull) {
                        int need = KEEP - K;        // 36
                        ulonglong2 slo = *(const ulonglong2*)&colM[64 + lane][0];
                        ulonglong2 shi = *(const ulonglong2*)&colM[64 + lane][2];
                        unsigned long long mm = U1;
                        int pk = __popcll(U1);
                        if (pk > need) {
                            int p = nth_set_bit(U1, need - 1);
                            mm = U1 & ((2ull << p) - 1ull);
                            pk = need;
                        }
                        bool m2 = ((mm >> lane) & 1ull) != 0ull;
                        unsigned long long w1 = m2 ? slo.y : 0ull;
                        unsigned long long w2 = m2 ? shi.x : 0ull;
                        unsigned long long w3 = m2 ? shi.y : 0ull;
                        #pragma unroll
                        for (int d = 1; d < 64; d <<= 1) {
                            w1 |= __shfl_xor(w1, d); w2 |= __shfl_xor(w2, d); w3 |= __shfl_xor(w3, d);
                        }
                        if ((w1 & mm) == 0ull) {
                            if (lane < pk) kIB = 64 + nth_set_bit(mm, lane);  // keep idx 64+lane (K==64)
                            K += pk;
                            U1 &= ~mm; U1 &= ~w1; U2 &= ~w2; U3 &= ~w3;
                        }
                        // dirty -> state untouched; serial engine continues from K=64
                    }
                }
                // dirty -> state untouched; serial engine runs from scratch
            }

            // serial engine: exact greedy continuation from (U, K) state
            while (K < KEEP) {
                int i;
                if (U0) i = (int)__ffsll(U0) - 1;
                else if (U1) i = 64 + (int)__ffsll(U1) - 1;
                else if (U2) i = 128 + (int)__ffsll(U2) - 1;
                else if (U3) i = 192 + (int)__ffsll(U3) - 1;
                else break;
                ulonglong2 r01 = *(const ulonglong2*)&colM[i][0];   // broadcast
                ulonglong2 r23 = *(const ulonglong2*)&colM[i][2];
                if (i < 64)       U0 &= ~(1ull << i);
                else if (i < 128) U1 &= ~(1ull << (i - 64));
                else if (i < 192) U2 &= ~(1ull << (i - 128));
                else              U3 &= ~(1ull << (i - 192));
                U0 &= ~r01.x; U1 &= ~r01.y; U2 &= ~r23.x; U3 &= ~r23.y;
                if (K < 64) { if (lane == K) kIA = i; }
                else        { if (lane == K - 64) kIB = i; }
                K++;
            }
            if (kIA >= 0) { kb0 = bBoxS[kIA]; ks0 = __uint_as_float(sKeyS[kIA]); }
            if (kIB >= 0) { kb1 = bBoxS[kIB]; ks1 = __uint_as_float(sKeyS[kIB]); }
            // mid-walk beyond matrix (cnt > MTX; rare)
            for (int i = lim; i < cnt && K < KEEP; ++i) {
                float4 bx = bBoxS[i];
                bool sup = false;
                if (lane < K)      sup = iou_gt(bx, kb0);
                if (64 + lane < K) sup = sup || iou_gt(bx, kb1);
                if (!__any(sup ? 1 : 0)) {
                    float sc = __uint_as_float(sKeyS[i]);
                    if (K < 64) { if (lane == K)      { kb0 = bx; ks0 = sc; } }
                    else        { if (lane == K - 64) { kb1 = bx; ks1 = sc; } }
                    K++;
                }
            }
            __builtin_amdgcn_s_setprio(0);
            if (lane == 0) {
                shr[0] = (uint32_t)K;
                shr[1] = (uint32_t)cnt;
                shr[2] = (cnt > 0) ? sKeyS[cnt - 1] : 0xFFFFFFFFu;
                shr[3] = (cnt > 0) ? (uint32_t)sIdxS[cnt - 1] : 0xFFFFFFFFu;
            }
        }
        __syncthreads();
        int Kall = (int)shr[0]; int e = (int)shr[1];
        uint32_t cK = shr[2], cI = shr[3];

        // ---- phase 8: exact continuation via block argmax over LDS keys (rare)
        if (Kall < KEEP && e < PRETOPK) {
            for (;;) {
                if (tid == 0) sh64 = 0ull;
                __syncthreads();
                unsigned long long best = 0ull;
                for (int i = 0; i < 17; ++i) {
                    int n = tid + i * TBS;
                    if (n < NPTS) {
                        uint32_t k = sKey[n];
                        if (k > THRBITS && (k < cK || (k == cK && (uint32_t)n > cI))) {
                            unsigned long long v = ((unsigned long long)k << 32) | (unsigned long long)(NPTS - 1 - n);
                            if (v > best) best = v;
                        }
                    }
                }
                if (best) atomicMax(&sh64, best);
                __syncthreads();
                unsigned long long bv = sh64;
                if (bv == 0ull) break;
                uint32_t k = (uint32_t)(bv >> 32);
                int n = NPTS - 1 - (int)(bv & 0xFFFFFFFFull);
                if (tid < 64) {
                    float4 bx = decode_one(n, b, bb0, bb1, bb2);
                    bool sup = false;
                    if (lane < K)      sup = iou_gt(bx, kb0);
                    if (64 + lane < K) sup = sup || iou_gt(bx, kb1);
                    if (!__any(sup ? 1 : 0)) {
                        float sc = __uint_as_float(k);
                        if (K < 64) { if (lane == K)      { kb0 = bx; ks0 = sc; } }
                        else        { if (lane == K - 64) { kb1 = bx; ks1 = sc; } }
                        K++;
                    }
                    if (lane == 0) shr[0] = (uint32_t)K;
                }
                __syncthreads();
                Kall = (int)shr[0];
                e++; cK = k; cI = (uint32_t)n;
                if (Kall >= KEEP || e >= PRETOPK) break;
            }
        }

        // ---- write per-class results
        if (tid < 64) {
            int off = (b * NCLS + c) * KEEP;
            float4 z = make_float4(0.f, 0.f, 0.f, 0.f);
            keptScore[off + lane] = (lane < K) ? ks0 : -1.0f;
            keptBox[off + lane]   = (lane < K) ? kb0 : z;
            if (64 + lane < KEEP) {
                keptScore[off + 64 + lane] = (64 + lane < K) ? ks1 : -1.0f;
                keptBox[off + 64 + lane]   = (64 + lane < K) ? kb1 : z;
            }
        }
        // loop-top __syncthreads protects LDS reuse for the next stolen item
    }
}

// ---------------------------------------------------------------- final per-image topk (rebased radix, 1024 bins)
__global__ __launch_bounds__(TBT)
void topk_out(const float* __restrict__ keptScore, const float4* __restrict__ keptBox,
              float* __restrict__ out) {
    __shared__ __align__(16) uint32_t sHist[1024];
    __shared__ __align__(16) unsigned long long cPackT[CAPT + 16];
    __shared__ uint32_t sKeyS[CAPT];
    __shared__ uint16_t sIdxS[CAPT];
    __shared__ uint32_t shr[4];
    int b = blockIdx.x, tid = threadIdx.x, lane = tid & 63;
    const int TOT = NCLS * KEEP;

    uint32_t rKey[NREGT];
    #pragma unroll
    for (int i = 0; i < NREGT; ++i) {
        int n = tid + i * TBT;
        uint32_t key = 0u;
        if (n < TOT) {
            float s = keptScore[b * TOT + n];
            key = (s > 0.f) ? __float_as_uint(s) : 0u;   // kept scores are always > 0.01
        }
        rKey[i] = key;
    }

    uint32_t prefix = 0, carry = 0, Tsel = 0;
    for (int level = 0;; ++level) {
        __syncthreads();
        if (level == 2) { if (tid < 64) sHist[tid] = 0; } else sHist[tid] = 0;
        __syncthreads();
        #pragma unroll
        for (int i = 0; i < NREGT; ++i) {
            uint32_t k = rKey[i];
            if (k > 0u) {
                uint32_t kp = k - BASEK;
                if (level == 0) atomicAdd(&sHist[kp >> 16], 1u);
                else if (level == 1) { if ((kp >> 16) == (prefix >> 16)) atomicAdd(&sHist[(kp >> 6) & 1023u], 1u); }
                else { if ((kp >> 6) == (prefix >> 6)) atomicAdd(&sHist[kp & 63u], 1u); }
            }
        }
        __syncthreads();
        if (tid < 64) {
            if (level < 2) scan_hist1024(sHist, (uint32_t)KEEP, (uint32_t)CAPT, carry, prefix, level == 0 ? 16 : 6, shr, lane);
            else           scan_hist64_final(sHist, (uint32_t)KEEP, (uint32_t)CAPT, carry, prefix, shr, lane);
        }
        __syncthreads();
        if (shr[1] == 0u) { Tsel = shr[0]; break; }
        prefix = shr[2]; carry = shr[3];
    }
    __syncthreads();
    if (tid == 0) shr[3] = 0u;
    __syncthreads();
    #pragma unroll
    for (int i = 0; i < NREGT; ++i) {
        uint32_t k = rKey[i];
        if (k > 0u && (k - BASEK) >= Tsel) {
            uint32_t s = atomicAdd(&shr[3], 1u);
            if (s < CAPT) cPackT[s] = ((unsigned long long)k << 32) | (uint32_t)(0xFFFFu - (tid + i * TBT));
        }
    }
    __syncthreads();
    int cnt = (int)shr[3]; if (cnt > CAPT) cnt = CAPT;
    if (tid < 16) cPackT[cnt + tid] = 0ull;
    __syncthreads();

    if (tid < ((cnt + 63) & ~63)) {
        bool h0 = tid < cnt;
        unsigned long long my = h0 ? cPackT[tid] : 0ull;
        int r0 = 0;
        const ulonglong2* cp2 = (const ulonglong2*)cPackT;
        int nb16 = (cnt + 15) >> 4;
        for (int jb = 0; jb < nb16; ++jb) {
            ulonglong2 p0 = cp2[jb * 8 + 0], p1 = cp2[jb * 8 + 1], p2 = cp2[jb * 8 + 2], p3 = cp2[jb * 8 + 3];
            ulonglong2 p4 = cp2[jb * 8 + 4], p5 = cp2[jb * 8 + 5], p6 = cp2[jb * 8 + 6], p7 = cp2[jb * 8 + 7];
            r0 += (p0.x > my) + (p0.y > my) + (p1.x > my) + (p1.y > my)
                + (p2.x > my) + (p2.y > my) + (p3.x > my) + (p3.y > my)
                + (p4.x > my) + (p4.y > my) + (p5.x > my) + (p5.y > my)
                + (p6.x > my) + (p6.y > my) + (p7.x > my) + (p7.y > my);
        }
        if (h0) {
            sKeyS[r0] = (uint32_t)(my >> 32);
            sIdxS[r0] = (uint16_t)(0xFFFFu - (uint32_t)(my & 0xFFFFu));
        }
    }
    __syncthreads();

    if (tid < KEEP) {
        bool valid = tid < cnt;
        int fi = valid ? (int)sIdxS[tid] : 0;
        float sc = valid ? __uint_as_float(sKeyS[tid]) : 0.f;
        float4 bx = valid ? keptBox[b * TOT + fi] : make_float4(0.f, 0.f, 0.f, 0.f);
        float cls = valid ? (float)(fi / KEEP) : -1.0f;
        float* boxOut = out + NB + (b * KEEP + tid) * 4;
        boxOut[0] = bx.x; boxOut[1] = bx.y; boxOut[2] = bx.z; boxOut[3] = bx.w;
        out[NB + NB * KEEP * 4 + b * KEEP + tid] = sc;
        out[NB + NB * KEEP * 4 + NB * KEEP + b * KEEP + tid] = cls;
    }
    if (tid == 0) out[b] = (float)((cnt < KEEP) ? cnt : KEEP);
}

// ---------------------------------------------------------------- launch
extern "C" void kernel_launch(void* const* d_in, const int* in_sizes, int n_in,
                              void* d_out, int out_size, void* d_ws, size_t ws_size,
                              hipStream_t stream) {
    const float* cls0 = (const float*)d_in[0];
    const float* bb0  = (const float*)d_in[1];
    const float* obj0 = (const float*)d_in[2];
    const float* cls1 = (const float*)d_in[3];
    const float* bb1  = (const float*)d_in[4];
    const float* obj1 = (const float*)d_in[5];
    const float* cls2 = (const float*)d_in[6];
    const float* bb2  = (const float*)d_in[7];
    const float* obj2 = (const float*)d_in[8];
    float* out = (float*)d_out;

    char* ws = (char*)d_ws;
    float*    keptScore = (float*)(ws);                  //   256,000 B
    float4*   keptBox   = (float4*)(ws + 256000);        // 1,024,000 B
    uint32_t* gIdx      = (uint32_t*)(ws + 1280000);     //        64 B (work-steal counter)

    hipMemsetAsync(gIdx, 0, 64, stream);   // reset steal counter each launch (graph-capture safe)
    select_nms<<<NBLK, TBS, 0, stream>>>(cls0, bb0, obj0, cls1, bb1, obj1,
                                         cls2, bb2, obj2, gIdx, keptScore, keptBox);
    topk_out<<<NB, TBT, 0, stream>>>(keptScore, keptBox, out);
}

// Round 12
// 140.396 us; speedup vs baseline: 1.2981x; 1.2981x over previous
//
#include <hip/hip_runtime.h>
#include <math.h>
#include <stdint.h>

#define NCLS   80
#define NPTS   8400
#define KEEP   100
#define PRETOPK 5000
#define NB     8
#define THRBITS 0x3C23D70Au   // bits of 0.01f (scores positive floats -> int-ordered)
#define BASEK   0x3C000000u   // all candidate keys in (THRBITS, 0x3F800000): key-BASEK is 26-bit

#define TBS    512            // select block size (8 waves; 3 blocks/CU by LDS)
#define CAPF   320            // candidate cap
#define NEEDF  128u           // selection target (>= KEEP; phase-8 continuation is exact regardless)
#define MTX    256            // suppression-matrix size
#define NW4    2100           // NPTS / 4 (uint4 words)

#define TBT    1024           // topk block size
#define NREGT  8              // 8000/1024
#define CAPT   512

__device__ __forceinline__ float sigmoidf_(float x) { return 1.0f / (1.0f + expf(-x)); }

__device__ __forceinline__ float4 decode_one(int n, int b,
        const float* bb0, const float* bb1, const float* bb2) {
    const float* bb; int base, HW, x, y; float s;
    if (n < 6400)      { bb = bb0; base = n;        HW = 6400; s = 8.f;  y = base / 80; x = base - y * 80; }
    else if (n < 8000) { bb = bb1; base = n - 6400; HW = 1600; s = 16.f; y = base / 40; x = base - y * 40; }
    else               { bb = bb2; base = n - 8000; HW = 400;  s = 32.f; y = base / 20; x = base - y * 20; }
    const float* p = bb + (size_t)b * 4 * HW + base;
    float v0 = p[0], v1 = p[HW], v2 = p[2 * HW], v3 = p[3 * HW];
    float cx = v0 * s + x * s, cy = v1 * s + y * s;
    float w = expf(v2) * s, h = expf(v3) * s;
    return make_float4(cx - 0.5f * w, cy - 0.5f * h, cx + 0.5f * w, cy + 0.5f * h);
}

__device__ __forceinline__ bool iou_gt(float4 a, float4 c) {
    float tlx = fmaxf(a.x, c.x), tly = fmaxf(a.y, c.y);
    float brx = fminf(a.z, c.z), bry = fminf(a.w, c.w);
    float w = fmaxf(brx - tlx, 0.f), h = fmaxf(bry - tly, 0.f);
    float inter = w * h;
    float a1 = (a.z - a.x) * (a.w - a.y);
    float a2 = (c.z - c.x) * (c.w - c.y);
    return inter / (a1 + a2 - inter + 1e-6f) > 0.65f;
}

// position of the r-th (0-based) set bit of v; precondition r < popcll(v)
__device__ __forceinline__ int nth_set_bit(unsigned long long v, int r) {
    int pos = 0;
    uint32_t x = (uint32_t)v;
    int c = __popc(x);
    if (r >= c) { r -= c; x = (uint32_t)(v >> 32); pos = 32; }
    c = __popc(x & 0xFFFFu); if (r >= c) { r -= c; x >>= 16; pos += 16; }
    c = __popc(x & 0xFFu);   if (r >= c) { r -= c; x >>= 8;  pos += 8; }
    c = __popc(x & 0xFu);    if (r >= c) { r -= c; x >>= 4;  pos += 4; }
    c = __popc(x & 0x3u);    if (r >= c) { r -= c; x >>= 2;  pos += 2; }
    c = __popc(x & 0x1u);    if (r >= c) { pos += 1; }
    return pos;
}

// ---- shared radix-scan helpers (operate on rebased 26-bit keys) ----
__device__ __forceinline__ void scan_hist1024(const uint32_t* sHist, uint32_t need, uint32_t cap,
                                              uint32_t carry, uint32_t prefix, int shift,
                                              uint32_t* shr, int lane) {
    const uint4* hv = (const uint4*)sHist;
    uint4 q0 = hv[lane * 4], q1 = hv[lane * 4 + 1], q2 = hv[lane * 4 + 2], q3 = hv[lane * 4 + 3];
    uint32_t csum = q0.x + q0.y + q0.z + q0.w + q1.x + q1.y + q1.z + q1.w
                  + q2.x + q2.y + q2.z + q2.w + q3.x + q3.y + q3.z + q3.w;
    uint32_t suf = csum;
    #pragma unroll
    for (int d = 1; d < 64; d <<= 1) {
        uint32_t t = (uint32_t)__shfl_down((int)suf, d);
        if (lane + d < 64) suf += t;
    }
    unsigned long long m = __ballot(carry + suf >= need);
    if (!m) { if (lane == 0) { shr[1] = 0u; shr[0] = 0u; } return; }
    int l1 = 63 - __clzll(m);
    uint32_t carry2 = carry + (uint32_t)__shfl((int)suf, l1) - (uint32_t)__shfl((int)csum, l1);
    uint32_t c2 = (lane < 16) ? sHist[l1 * 16 + lane] : 0u;
    uint32_t suf2 = c2;
    #pragma unroll
    for (int d = 1; d < 16; d <<= 1) {
        uint32_t t = (uint32_t)__shfl_down((int)suf2, d);
        if (lane + d < 16) suf2 += t;
    }
    unsigned long long m2 = __ballot(lane < 16 && (carry2 + suf2 >= need));
    int t2 = m2 ? (63 - __clzll(m2)) : 0;
    uint32_t suf2L = (uint32_t)__shfl((int)suf2, t2);
    uint32_t c2L   = (uint32_t)__shfl((int)c2, t2);
    int bin = l1 * 16 + t2;
    uint32_t cAbove = carry2 + suf2L - c2L;
    uint32_t cntIncl = cAbove + c2L;
    if (lane == 0) {
        if (cntIncl <= cap) { shr[1] = 0u; shr[0] = prefix | ((uint32_t)bin << shift); }
        else { shr[1] = 1u; shr[2] = prefix | ((uint32_t)bin << shift); shr[3] = cAbove; }
    }
}

__device__ __forceinline__ void scan_hist64_final(const uint32_t* sHist, uint32_t need, uint32_t cap,
                                                  uint32_t carry, uint32_t prefix,
                                                  uint32_t* shr, int lane) {
    uint32_t c2 = sHist[lane];
    uint32_t suf2 = c2;
    #pragma unroll
    for (int d = 1; d < 64; d <<= 1) {
        uint32_t t = (uint32_t)__shfl_down((int)suf2, d);
        if (lane + d < 64) suf2 += t;
    }
    unsigned long long m2 = __ballot(carry + suf2 >= need);
    int t2 = m2 ? (63 - __clzll(m2)) : 0;
    uint32_t suf2L = (uint32_t)__shfl((int)suf2, t2);
    uint32_t c2L   = (uint32_t)__shfl((int)c2, t2);
    uint32_t cAbove = carry + suf2L - c2L;
    uint32_t cntIncl = cAbove + c2L;
    if (lane == 0) {
        shr[1] = 0u;
        shr[0] = (cntIncl <= cap) ? (prefix | (uint32_t)t2)
                                  : ((prefix | (uint32_t)t2) + 1u);  // exclude exact tie-key; continuation recovers
    }
}

// ================================================================ fused per-(b,c) select + sort + NMS
// Static grid (640 blocks, b=bc&7 XCD locality) — R9 structure, R10-validated NEEDF/CAPF.
// LDS: sKey 33600 + uMem 8192 + sKeyS 1280 + sIdxS 640 + bBoxS 5120 + shr 16 + sh64 8 = 48856 -> 3 blocks/CU
// uMem aliases: { sHist(4096) + cPack(2688) } <-> colM(8192); barriers separate lifetimes.
__global__ __launch_bounds__(TBS, 6)
void select_nms(const float* __restrict__ cls0, const float* __restrict__ bb0,
                const float* __restrict__ o0,
                const float* __restrict__ cls1, const float* __restrict__ bb1,
                const float* __restrict__ o1,
                const float* __restrict__ cls2, const float* __restrict__ bb2,
                const float* __restrict__ o2,
                float* __restrict__ keptScore, float4* __restrict__ keptBox) {
    __shared__ __align__(16) uint32_t sKey[NPTS];                // 33.6 KB
    __shared__ __align__(16) char uMem[8192];                    // 8 KB (aliased)
    __shared__ uint32_t sKeyS[CAPF];
    __shared__ uint16_t sIdxS[CAPF];
    __shared__ __align__(16) float4 bBoxS[CAPF];
    __shared__ uint32_t shr[4];
    __shared__ unsigned long long sh64;

    uint32_t* sHist = (uint32_t*)uMem;                           // 4096 B
    unsigned long long* cPack = (unsigned long long*)(uMem + 4096); // (CAPF+16)*8 = 2688 B
    typedef unsigned long long ull4[4];
    ull4* colM = (ull4*)uMem;                                    // 8192 B, aliases sHist+cPack

    int bc = blockIdx.x;
    int b = bc & 7;                  // XCD-locality: image b -> XCD b
    int c = bc >> 3;
    int tid = threadIdx.x, lane = tid & 63;

    // ---- phase 1: keygen (float4 loads, fused obj sigmoid) -> LDS + rebased level-0 histogram
    sHist[tid] = 0; sHist[tid + TBS] = 0;
    __syncthreads();
    uint4* sKey4 = (uint4*)sKey;
    #pragma unroll
    for (int i = 0; i < 5; ++i) {
        int w = tid + i * TBS;
        if (w < NW4) {
            int n = w << 2;
            const float* cp; const float* op;
            if (w < 1600)      { cp = cls0 + ((size_t)b * NCLS + c) * 6400 + n;          op = o0 + (size_t)b * 6400 + n; }
            else if (w < 2000) { cp = cls1 + ((size_t)b * NCLS + c) * 1600 + (n - 6400); op = o1 + (size_t)b * 1600 + (n - 6400); }
            else               { cp = cls2 + ((size_t)b * NCLS + c) * 400 + (n - 8000);  op = o2 + (size_t)b * 400 + (n - 8000); }
            float4 cv = *(const float4*)cp;
            float4 ov = *(const float4*)op;
            uint32_t k0 = __float_as_uint(sigmoidf_(cv.x) * sigmoidf_(ov.x));
            uint32_t k1 = __float_as_uint(sigmoidf_(cv.y) * sigmoidf_(ov.y));
            uint32_t k2 = __float_as_uint(sigmoidf_(cv.z) * sigmoidf_(ov.z));
            uint32_t k3 = __float_as_uint(sigmoidf_(cv.w) * sigmoidf_(ov.w));
            sKey4[w] = make_uint4(k0, k1, k2, k3);
            if (k0 > THRBITS) atomicAdd(&sHist[(k0 - BASEK) >> 16], 1u);
            if (k1 > THRBITS) atomicAdd(&sHist[(k1 - BASEK) >> 16], 1u);
            if (k2 > THRBITS) atomicAdd(&sHist[(k2 - BASEK) >> 16], 1u);
            if (k3 > THRBITS) atomicAdd(&sHist[(k3 - BASEK) >> 16], 1u);
        }
    }
    __syncthreads();

    // ---- phase 2: exact radix threshold selection on 26-bit rebased keys (10/10/6 bits)
    uint32_t prefix = 0, carry = 0, Tsel = 0;
    const uint4* k4 = (const uint4*)sKey;
    for (int level = 0;; ++level) {
        if (tid < 64) {
            if (level < 2) scan_hist1024(sHist, NEEDF, CAPF, carry, prefix, level == 0 ? 16 : 6, shr, lane);
            else           scan_hist64_final(sHist, NEEDF, CAPF, carry, prefix, shr, lane);
        }
        __syncthreads();
        if (shr[1] == 0u) { Tsel = shr[0]; break; }
        prefix = shr[2]; carry = shr[3];
        int nl = level + 1;
        if (nl == 2) { if (tid < 64) sHist[tid] = 0; } else { sHist[tid] = 0; sHist[tid + TBS] = 0; }
        __syncthreads();
        #pragma unroll
        for (int i = 0; i < 5; ++i) {
            int w = tid + i * TBS;
            if (w < NW4) {
                uint4 q = k4[w];
                #pragma unroll
                for (int j = 0; j < 4; ++j) {
                    uint32_t k = (j == 0) ? q.x : (j == 1) ? q.y : (j == 2) ? q.z : q.w;
                    if (k > THRBITS) {
                        uint32_t kp = k - BASEK;
                        if (nl == 1) { if ((kp >> 16) == (prefix >> 16)) atomicAdd(&sHist[(kp >> 6) & 1023u], 1u); }
                        else         { if ((kp >> 6)  == (prefix >> 6))  atomicAdd(&sHist[kp & 63u], 1u); }
                    }
                }
            }
        }
        __syncthreads();
    }
    __syncthreads();
    if (tid == 0) shr[3] = 0u;
    __syncthreads();

    // ---- phase 3: compact from LDS keys (packed u64: key<<32 | (0xFFFF - n))
    #pragma unroll
    for (int i = 0; i < 5; ++i) {
        int w = tid + i * TBS;
        if (w < NW4) {
            uint4 q = k4[w];
            int n = w << 2;
            #pragma unroll
            for (int j = 0; j < 4; ++j) {
                uint32_t k = (j == 0) ? q.x : (j == 1) ? q.y : (j == 2) ? q.z : q.w;
                if (k > THRBITS && (k - BASEK) >= Tsel) {
                    uint32_t s = atomicAdd(&shr[3], 1u);
                    if (s < CAPF) cPack[s] = ((unsigned long long)k << 32) | (uint32_t)(0xFFFFu - (n + j));
                }
            }
        }
    }
    __syncthreads();
    int cnt = (int)shr[3]; if (cnt > CAPF) cnt = CAPF;
    if (tid < 16) cPack[cnt + tid] = 0ull;
    __syncthreads();

    // ---- phase 4: rank-sort, participating waves only, 16 cands/iter (b128 reads)
    if (tid < ((cnt + 63) & ~63)) {
        bool h0 = tid < cnt;
        unsigned long long my = h0 ? cPack[tid] : 0ull;
        int r0 = 0;
        const ulonglong2* cp2 = (const ulonglong2*)cPack;
        int nb16 = (cnt + 15) >> 4;
        for (int jb = 0; jb < nb16; ++jb) {
            ulonglong2 p0 = cp2[jb * 8 + 0], p1 = cp2[jb * 8 + 1], p2 = cp2[jb * 8 + 2], p3 = cp2[jb * 8 + 3];
            ulonglong2 p4 = cp2[jb * 8 + 4], p5 = cp2[jb * 8 + 5], p6 = cp2[jb * 8 + 6], p7 = cp2[jb * 8 + 7];
            r0 += (p0.x > my) + (p0.y > my) + (p1.x > my) + (p1.y > my)
                + (p2.x > my) + (p2.y > my) + (p3.x > my) + (p3.y > my)
                + (p4.x > my) + (p4.y > my) + (p5.x > my) + (p5.y > my)
                + (p6.x > my) + (p6.y > my) + (p7.x > my) + (p7.y > my);
        }
        if (h0) {
            sKeyS[r0] = (uint32_t)(my >> 32);
            sIdxS[r0] = (uint16_t)(0xFFFFu - (uint32_t)(my & 0xFFFFu));
        }
    }
    __syncthreads();

    // ---- phase 5: gather + inline-decode candidate boxes
    if (tid < cnt) bBoxS[tid] = decode_one(sIdxS[tid], b, bb0, bb1, bb2);
    __syncthreads();
    // (cPack/sHist dead from here on; colM may now overwrite uMem)

    // ---- phase 6: UPPER-TRIANGLE suppression bitmatrix (exact: walk only consumes j>i bits)
    int lim = (cnt < MTX) ? cnt : MTX;
    #pragma unroll
    for (int pp = 0; pp < 2; ++pp) {
        int t2 = tid + pp * TBS;
        int cand = t2 & 255, rb = t2 >> 8;
        int j0 = rb << 6;
        unsigned long long m = 0ull;
        if (cand < lim && j0 + 63 > cand) {
            float4 bcx = bBoxS[cand];
            #pragma unroll 8
            for (int jj = 0; jj < 64; ++jj)
                if (iou_gt(bBoxS[j0 + jj], bcx)) m |= 1ull << jj;
            if (j0 <= cand) m &= ~((2ull << (cand - j0)) - 1ull);  // keep only j > cand
        }
        colM[cand][rb] = m;
    }
    __syncthreads();

    // ---- phase 7: batch probes (all-kept fast path) + serial walk engine (exact greedy)
    float4 kb0 = make_float4(0.f, 0.f, 0.f, 0.f), kb1 = kb0;
    float ks0 = -1.0f, ks1 = -1.0f;
    int K = 0;
    if (tid < 64) {
        __builtin_amdgcn_s_setprio(1);
        unsigned long long U0, U1, U2, U3;
        U0 = (lim >= 64) ? ~0ull : ((lim > 0) ? ((1ull << lim) - 1) : 0ull);
        U1 = (lim >= 128) ? ~0ull : ((lim > 64) ? ((1ull << (lim - 64)) - 1) : 0ull);
        U2 = (lim >= 192) ? ~0ull : ((lim > 128) ? ((1ull << (lim - 128)) - 1) : 0ull);
        U3 = (lim >= 256) ? ~0ull : ((lim > 192) ? ((1ull << (lim - 192)) - 1) : 0ull);
        int kIA = -1, kIB = -1;

        // probe A: first n0=min(lim,64) candidates mutually non-suppressing? -> keep all at once
        int n0 = (lim < 64) ? lim : 64;
        if (n0 > 0) {
            ulonglong2 rlo = *(const ulonglong2*)&colM[lane][0];
            ulonglong2 rhi = *(const ulonglong2*)&colM[lane][2];
            bool mem = lane < n0;
            unsigned long long v0 = mem ? rlo.x : 0ull, v1 = mem ? rlo.y : 0ull;
            unsigned long long v2 = mem ? rhi.x : 0ull, v3 = mem ? rhi.y : 0ull;
            #pragma unroll
            for (int d = 1; d < 64; d <<= 1) {
                v0 |= __shfl_xor(v0, d); v1 |= __shfl_xor(v1, d);
                v2 |= __shfl_xor(v2, d); v3 |= __shfl_xor(v3, d);
            }
            if ((v0 & U0) == 0ull) {
                if (lane < n0) kIA = lane;      // keep-index lane <- candidate lane
                K = n0;
                U0 = 0ull; U1 &= ~v1; U2 &= ~v2; U3 &= ~v3;
                // probe B: next need=KEEP-K remaining candidates of chunk 1 (K==64 here iff lim>64)
                if (lim > 64 && U1 != 0ull) {
                    int need = KEEP - K;        // 36
                    ulonglong2 slo = *(const ulonglong2*)&colM[64 + lane][0];
                    ulonglong2 shi = *(const ulonglong2*)&colM[64 + lane][2];
                    unsigned long long mm = U1;
                    int pk = __popcll(U1);
                    if (pk > need) {
                        int p = nth_set_bit(U1, need - 1);
                        mm = U1 & ((2ull << p) - 1ull);
                        pk = need;
                    }
                    bool m2 = ((mm >> lane) & 1ull) != 0ull;
                    unsigned long long w1 = m2 ? slo.y : 0ull;
                    unsigned long long w2 = m2 ? shi.x : 0ull;
                    unsigned long long w3 = m2 ? shi.y : 0ull;
                    #pragma unroll
                    for (int d = 1; d < 64; d <<= 1) {
                        w1 |= __shfl_xor(w1, d); w2 |= __shfl_xor(w2, d); w3 |= __shfl_xor(w3, d);
                    }
                    if ((w1 & mm) == 0ull) {
                        if (lane < pk) kIB = 64 + nth_set_bit(mm, lane);  // keep idx 64+lane (K==64)
                        K += pk;
                        U1 &= ~mm; U1 &= ~w1; U2 &= ~w2; U3 &= ~w3;
                    }
                    // dirty -> state untouched; serial engine continues from K=64
                }
            }
            // dirty -> state untouched; serial engine runs from scratch
        }

        // serial engine: exact greedy continuation from (U, K) state
        while (K < KEEP) {
            int i;
            if (U0) i = (int)__ffsll(U0) - 1;
            else if (U1) i = 64 + (int)__ffsll(U1) - 1;
            else if (U2) i = 128 + (int)__ffsll(U2) - 1;
            else if (U3) i = 192 + (int)__ffsll(U3) - 1;
            else break;
            ulonglong2 r01 = *(const ulonglong2*)&colM[i][0];   // broadcast
            ulonglong2 r23 = *(const ulonglong2*)&colM[i][2];
            if (i < 64)       U0 &= ~(1ull << i);
            else if (i < 128) U1 &= ~(1ull << (i - 64));
            else if (i < 192) U2 &= ~(1ull << (i - 128));
            else              U3 &= ~(1ull << (i - 192));
            U0 &= ~r01.x; U1 &= ~r01.y; U2 &= ~r23.x; U3 &= ~r23.y;
            if (K < 64) { if (lane == K) kIA = i; }
            else        { if (lane == K - 64) kIB = i; }
            K++;
        }
        if (kIA >= 0) { kb0 = bBoxS[kIA]; ks0 = __uint_as_float(sKeyS[kIA]); }
        if (kIB >= 0) { kb1 = bBoxS[kIB]; ks1 = __uint_as_float(sKeyS[kIB]); }
        // mid-walk beyond matrix (cnt > MTX; rare)
        for (int i = lim; i < cnt && K < KEEP; ++i) {
            float4 bx = bBoxS[i];
            bool sup = false;
            if (lane < K)      sup = iou_gt(bx, kb0);
            if (64 + lane < K) sup = sup || iou_gt(bx, kb1);
            if (!__any(sup ? 1 : 0)) {
                float sc = __uint_as_float(sKeyS[i]);
                if (K < 64) { if (lane == K)      { kb0 = bx; ks0 = sc; } }
                else        { if (lane == K - 64) { kb1 = bx; ks1 = sc; } }
                K++;
            }
        }
        __builtin_amdgcn_s_setprio(0);
        if (lane == 0) {
            shr[0] = (uint32_t)K;
            shr[1] = (uint32_t)cnt;
            shr[2] = (cnt > 0) ? sKeyS[cnt - 1] : 0xFFFFFFFFu;
            shr[3] = (cnt > 0) ? (uint32_t)sIdxS[cnt - 1] : 0xFFFFFFFFu;
        }
    }
    __syncthreads();
    int Kall = (int)shr[0]; int e = (int)shr[1];
    uint32_t cK = shr[2], cI = shr[3];

    // ---- phase 8: exact continuation via block argmax over LDS keys (rare)
    if (Kall < KEEP && e < PRETOPK) {
        for (;;) {
            if (tid == 0) sh64 = 0ull;
            __syncthreads();
            unsigned long long best = 0ull;
            for (int i = 0; i < 17; ++i) {
                int n = tid + i * TBS;
                if (n < NPTS) {
                    uint32_t k = sKey[n];
                    if (k > THRBITS && (k < cK || (k == cK && (uint32_t)n > cI))) {
                        unsigned long long v = ((unsigned long long)k << 32) | (unsigned long long)(NPTS - 1 - n);
                        if (v > best) best = v;
                    }
                }
            }
            if (best) atomicMax(&sh64, best);
            __syncthreads();
            unsigned long long bv = sh64;
            if (bv == 0ull) break;
            uint32_t k = (uint32_t)(bv >> 32);
            int n = NPTS - 1 - (int)(bv & 0xFFFFFFFFull);
            if (tid < 64) {
                float4 bx = decode_one(n, b, bb0, bb1, bb2);
                bool sup = false;
                if (lane < K)      sup = iou_gt(bx, kb0);
                if (64 + lane < K) sup = sup || iou_gt(bx, kb1);
                if (!__any(sup ? 1 : 0)) {
                    float sc = __uint_as_float(k);
                    if (K < 64) { if (lane == K)      { kb0 = bx; ks0 = sc; } }
                    else        { if (lane == K - 64) { kb1 = bx; ks1 = sc; } }
                    K++;
                }
                if (lane == 0) shr[0] = (uint32_t)K;
            }
            __syncthreads();
            Kall = (int)shr[0];
            e++; cK = k; cI = (uint32_t)n;
            if (Kall >= KEEP || e >= PRETOPK) break;
        }
    }

    // ---- write per-class results
    if (tid < 64) {
        int off = (b * NCLS + c) * KEEP;
        float4 z = make_float4(0.f, 0.f, 0.f, 0.f);
        keptScore[off + lane] = (lane < K) ? ks0 : -1.0f;
        keptBox[off + lane]   = (lane < K) ? kb0 : z;
        if (64 + lane < KEEP) {
            keptScore[off + 64 + lane] = (64 + lane < K) ? ks1 : -1.0f;
            keptBox[off + 64 + lane]   = (64 + lane < K) ? kb1 : z;
        }
    }
}

// ---------------------------------------------------------------- final per-image topk (rebased radix, 1024 bins)
__global__ __launch_bounds__(TBT)
void topk_out(const float* __restrict__ keptScore, const float4* __restrict__ keptBox,
              float* __restrict__ out) {
    __shared__ __align__(16) uint32_t sHist[1024];
    __shared__ __align__(16) unsigned long long cPackT[CAPT + 16];
    __shared__ uint32_t sKeyS[CAPT];
    __shared__ uint16_t sIdxS[CAPT];
    __shared__ uint32_t shr[4];
    int b = blockIdx.x, tid = threadIdx.x, lane = tid & 63;
    const int TOT = NCLS * KEEP;

    uint32_t rKey[NREGT];
    #pragma unroll
    for (int i = 0; i < NREGT; ++i) {
        int n = tid + i * TBT;
        uint32_t key = 0u;
        if (n < TOT) {
            float s = keptScore[b * TOT + n];
            key = (s > 0.f) ? __float_as_uint(s) : 0u;   // kept scores are always > 0.01
        }
        rKey[i] = key;
    }

    uint32_t prefix = 0, carry = 0, Tsel = 0;
    for (int level = 0;; ++level) {
        __syncthreads();
        if (level == 2) { if (tid < 64) sHist[tid] = 0; } else sHist[tid] = 0;
        __syncthreads();
        #pragma unroll
        for (int i = 0; i < NREGT; ++i) {
            uint32_t k = rKey[i];
            if (k > 0u) {
                uint32_t kp = k - BASEK;
                if (level == 0) atomicAdd(&sHist[kp >> 16], 1u);
                else if (level == 1) { if ((kp >> 16) == (prefix >> 16)) atomicAdd(&sHist[(kp >> 6) & 1023u], 1u); }
                else { if ((kp >> 6) == (prefix >> 6)) atomicAdd(&sHist[kp & 63u], 1u); }
            }
        }
        __syncthreads();
        if (tid < 64) {
            if (level < 2) scan_hist1024(sHist, (uint32_t)KEEP, (uint32_t)CAPT, carry, prefix, level == 0 ? 16 : 6, shr, lane);
            else           scan_hist64_final(sHist, (uint32_t)KEEP, (uint32_t)CAPT, carry, prefix, shr, lane);
        }
        __syncthreads();
        if (shr[1] == 0u) { Tsel = shr[0]; break; }
        prefix = shr[2]; carry = shr[3];
    }
    __syncthreads();
    if (tid == 0) shr[3] = 0u;
    __syncthreads();
    #pragma unroll
    for (int i = 0; i < NREGT; ++i) {
        uint32_t k = rKey[i];
        if (k > 0u && (k - BASEK) >= Tsel) {
            uint32_t s = atomicAdd(&shr[3], 1u);
            if (s < CAPT) cPackT[s] = ((unsigned long long)k << 32) | (uint32_t)(0xFFFFu - (tid + i * TBT));
        }
    }
    __syncthreads();
    int cnt = (int)shr[3]; if (cnt > CAPT) cnt = CAPT;
    if (tid < 16) cPackT[cnt + tid] = 0ull;
    __syncthreads();

    if (tid < ((cnt + 63) & ~63)) {
        bool h0 = tid < cnt;
        unsigned long long my = h0 ? cPackT[tid] : 0ull;
        int r0 = 0;
        const ulonglong2* cp2 = (const ulonglong2*)cPackT;
        int nb16 = (cnt + 15) >> 4;
        for (int jb = 0; jb < nb16; ++jb) {
            ulonglong2 p0 = cp2[jb * 8 + 0], p1 = cp2[jb * 8 + 1], p2 = cp2[jb * 8 + 2], p3 = cp2[jb * 8 + 3];
            ulonglong2 p4 = cp2[jb * 8 + 4], p5 = cp2[jb * 8 + 5], p6 = cp2[jb * 8 + 6], p7 = cp2[jb * 8 + 7];
            r0 += (p0.x > my) + (p0.y > my) + (p1.x > my) + (p1.y > my)
                + (p2.x > my) + (p2.y > my) + (p3.x > my) + (p3.y > my)
                + (p4.x > my) + (p4.y > my) + (p5.x > my) + (p5.y > my)
                + (p6.x > my) + (p6.y > my) + (p7.x > my) + (p7.y > my);
        }
        if (h0) {
            sKeyS[r0] = (uint32_t)(my >> 32);
            sIdxS[r0] = (uint16_t)(0xFFFFu - (uint32_t)(my & 0xFFFFu));
        }
    }
    __syncthreads();

    if (tid < KEEP) {
        bool valid = tid < cnt;
        int fi = valid ? (int)sIdxS[tid] : 0;
        float sc = valid ? __uint_as_float(sKeyS[tid]) : 0.f;
        float4 bx = valid ? keptBox[b * TOT + fi] : make_float4(0.f, 0.f, 0.f, 0.f);
        float cls = valid ? (float)(fi / KEEP) : -1.0f;
        float* boxOut = out + NB + (b * KEEP + tid) * 4;
        boxOut[0] = bx.x; boxOut[1] = bx.y; boxOut[2] = bx.z; boxOut[3] = bx.w;
        out[NB + NB * KEEP * 4 + b * KEEP + tid] = sc;
        out[NB + NB * KEEP * 4 + NB * KEEP + b * KEEP + tid] = cls;
    }
    if (tid == 0) out[b] = (float)((cnt < KEEP) ? cnt : KEEP);
}

// ---------------------------------------------------------------- launch
extern "C" void kernel_launch(void* const* d_in, const int* in_sizes, int n_in,
                              void* d_out, int out_size, void* d_ws, size_t ws_size,
                              hipStream_t stream) {
    const float* cls0 = (const float*)d_in[0];
    const float* bb0  = (const float*)d_in[1];
    const float* obj0 = (const float*)d_in[2];
    const float* cls1 = (const float*)d_in[3];
    const float* bb1  = (const float*)d_in[4];
    const float* obj1 = (const float*)d_in[5];
    const float* cls2 = (const float*)d_in[6];
    const float* bb2  = (const float*)d_in[7];
    const float* obj2 = (const float*)d_in[8];
    float* out = (float*)d_out;

    char* ws = (char*)d_ws;
    float*  keptScore = (float*)(ws);                  //   256,000 B
    float4* keptBox   = (float4*)(ws + 256000);        // 1,024,000 B

    select_nms<<<NB * NCLS, TBS, 0, stream>>>(cls0, bb0, obj0, cls1, bb1, obj1,
                                              cls2, bb2, obj2, keptScore, keptBox);
    topk_out<<<NB, TBT, 0, stream>>>(keptScore, keptBox, out);
}